// Round 3
// baseline (19070.880 us; speedup 1.0000x reference)
//
#include <hip/hip_runtime.h>
#include <hip/hip_cooperative_groups.h>

// PN_Critic: conv1d(k=1) -> 512-step LSTM -> time-sum -> fc1(relu) -> fc2
// B=256 S=512 D=128 H1=256 H2=512, gates=2048, combined K = 128+512 = 640.
//
// Round-2 changes vs round-0 design:
//  * grid.sync() per step (measured ~33us/step, 99% idle) replaced by a
//    16-WG group barrier (monotonic counter, agent-scope atomics), split
//    arrive/wait so next-step x staging overlaps the spin.
//  * B-fragments pinned in VGPRs via opaque asm (VGPR_Count was 112 ->
//    compiler was re-loading 40KB/wave/step from L2).
//  * A-tile XOR-swizzled (byte ^= (row&7)<<4), unpadded stride 640 shorts:
//    structural-minimum LDS banking (old pad gave 1.0e8 conflict cycles).

typedef __attribute__((ext_vector_type(8))) short s16x8;
typedef __attribute__((ext_vector_type(4))) float f32x4;
typedef __attribute__((ext_vector_type(2))) float f32x2;

#define B_   256
#define S_   512
#define D_   128
#define H1_  256
#define H2_  512
#define G4_  2048
#define K_   640

__device__ __forceinline__ unsigned short f2bf(float f) {
  union { float f; unsigned u; } v; v.f = f;
  unsigned r = v.u + 0x7FFFu + ((v.u >> 16) & 1u);   // round-nearest-even
  return (unsigned short)(r >> 16);
}
__device__ __forceinline__ float sigm(float x) { return 1.f / (1.f + __expf(-x)); }
__device__ __forceinline__ float tanh_(float x) { return 1.f - 2.f / (__expf(2.f * x) + 1.f); }

// ---------------- prep: build combined weight + bias (gate-interleaved rows) --
__global__ void prep_kernel(const float* __restrict__ conv_w, const float* __restrict__ conv_b,
                            const float* __restrict__ w_ih,   const float* __restrict__ b_ih,
                            const float* __restrict__ w_hh,   const float* __restrict__ b_hh,
                            unsigned short* __restrict__ Wc,  float* __restrict__ bias,
                            unsigned* __restrict__ barrier_cnt) {
  const int np = blockIdx.x;          // n' = 4*j + g
  const int g = np & 3, j = np >> 2;
  const int n = g * H2_ + j;          // original gate row
  const int tid = threadIdx.x;        // 128 threads

  if (np == 0 && tid < 16) barrier_cnt[tid * 32] = 0;  // zero group counters

  __shared__ float wrow[H1_];
  __shared__ float red[128];
  wrow[tid]       = w_ih[(size_t)n * H1_ + tid];
  wrow[tid + 128] = w_ih[(size_t)n * H1_ + tid + 128];
  __syncthreads();

  // x-projection part: k = tid (0..127)
  float acc = 0.f;
  for (int h1 = 0; h1 < H1_; ++h1)
    acc += wrow[h1] * conv_w[(size_t)h1 * D_ + tid];
  Wc[(size_t)np * K_ + tid] = f2bf(acc);

  // recurrent part: copy w_hh row (bf16)
  #pragma unroll
  for (int r = 0; r < 4; ++r)
    Wc[(size_t)np * K_ + 128 + tid + r * 128] = f2bf(w_hh[(size_t)n * H2_ + tid + r * 128]);

  // bias[n'] = b_ih + b_hh + w_ih@conv_b
  float p = wrow[tid] * conv_b[tid] + wrow[tid + 128] * conv_b[tid + 128];
  red[tid] = p;
  __syncthreads();
  for (int s = 64; s > 0; s >>= 1) {
    if (tid < s) red[tid] += red[tid + s];
    __syncthreads();
  }
  if (tid == 0) bias[np] = red[0] + b_ih[n] + b_hh[n];
}

// ---------------- persistent cooperative LSTM ------------------------------
__global__ __launch_bounds__(256, 1) void lstm_kernel(
    const float* __restrict__ x, const float* __restrict__ h0,
    const float* __restrict__ c0, const unsigned short* __restrict__ Wc,
    const float* __restrict__ bias, unsigned short* __restrict__ h_bf,
    float* __restrict__ pooled, unsigned* __restrict__ barrier_cnt) {
  cooperative_groups::grid_group grid = cooperative_groups::this_grid();

  const int wg = blockIdx.x;       // 256 WGs = 16 mg x 16 ng
  const int mg = wg & 15;          // batch rows mg*16 .. +16  (group id; stride-16
  const int ng = wg >> 4;          //   members land on one XCD under %8 heuristic)
  const int tid = threadIdx.x;
  const int wv = tid >> 6;         // wave 0..3: cols wv*32 within the 128
  const int lane = tid & 63;

  __shared__ unsigned short Alds[16 * K_];          // XOR-swizzled, stride 1280B/row
  __shared__ float gate_lds[4][16][33];
  __shared__ float bias_lds[128];

  unsigned* my_cnt = barrier_cnt + mg * 32;         // 128B-separated counters

  // --- B-slice (32 cols x K=640) into VGPRs, loaded once ---
  const int n0 = ng * 128 + wv * 32;
  s16x8 bfrag0[20], bfrag1[20];
  {
    const int bn0 = n0 + (lane & 15);
    const int bk = (lane >> 4) * 8;
    #pragma unroll
    for (int kk = 0; kk < 20; ++kk) {
      bfrag0[kk] = *(const s16x8*)(Wc + (size_t)bn0 * K_ + kk * 32 + bk);
      bfrag1[kk] = *(const s16x8*)(Wc + (size_t)(bn0 + 16) * K_ + kk * 32 + bk);
    }
  }
  // Pin fragments: opaque defs -> compiler cannot rematerialize the global
  // loads inside the t-loop (round-2 counters showed VGPR_Count=112, i.e.
  // weights were being re-fetched every step).
  #pragma unroll
  for (int kk = 0; kk < 20; ++kk)
    asm volatile("" : "+v"(bfrag0[kk]), "+v"(bfrag1[kk]));

  if (tid < 128) bias_lds[tid] = bias[ng * 128 + tid];

  // --- init h buffer 0 from h0 (each WG writes batch row b == wg) ---
  {
    const int gt = wg * 256 + tid;           // 0..65535
    #pragma unroll
    for (int e = 0; e < 2; ++e) {
      const int idx = gt * 2 + e;            // 0..131071
      h_bf[idx] = f2bf(h0[idx]);
    }
  }

  // --- per-lane cell state: 2 consecutive (b,j) pairs owned forever ---
  const int r_own = lane >> 2;               // pi=2*lane -> r = pi>>3 = lane>>2
  const int jl_own = 2 * (lane & 3);         // pi&7 = 2*(lane&3), +1
  const int b_own = mg * 16 + r_own;
  const int j_own = ng * 32 + wv * 8 + jl_own;
  f32x2 c_reg = *(const f32x2*)(c0 + (size_t)b_own * H2_ + j_own);
  f32x2 pool_acc = {0.f, 0.f};

  // staging geometry
  const int sr = tid >> 4, sct = tid & 15;   // 16 rows x 16 col-threads
  const int b_st = mg * 16 + sr;
  const unsigned row_base = sr * (K_ * 2);   // byte offset of row sr
  const unsigned swz_x = (row_base + sct * 16) ^ ((sr & 7) << 4);

  const int ar = lane & 15;                  // GEMM A row
  const int ahi = lane >> 4;                 // k-slice selector

  // prologue: stage x_0 into LDS x-part
  {
    const float* xp = x + ((size_t)b_st * S_ + 0) * D_ + sct * 8;
    f32x4 v0 = *(const f32x4*)xp;
    f32x4 v1 = *(const f32x4*)(xp + 4);
    s16x8 pk;
    pk[0] = (short)f2bf(v0[0]); pk[1] = (short)f2bf(v0[1]);
    pk[2] = (short)f2bf(v0[2]); pk[3] = (short)f2bf(v0[3]);
    pk[4] = (short)f2bf(v1[0]); pk[5] = (short)f2bf(v1[1]);
    pk[6] = (short)f2bf(v1[2]); pk[7] = (short)f2bf(v1[3]);
    *(s16x8*)((char*)Alds + swz_x) = pk;
  }

  grid.sync();   // once: h_bf init + barrier counters (prep) visible everywhere

  #pragma unroll 1
  for (int t = 0; t < S_; ++t) {
    const unsigned short* __restrict__ hin = h_bf + (t & 1) * (B_ * H2_);
    unsigned short* __restrict__ hout = h_bf + ((t + 1) & 1) * (B_ * H2_);

    // ---- stage h_{t-1} into A-tile h-part (swizzled) ----
    {
      const unsigned short* hrow = hin + (size_t)b_st * H2_ + sct * 32;
      #pragma unroll
      for (int q = 0; q < 4; ++q) {
        s16x8 hv = *(const s16x8*)(hrow + q * 8);
        unsigned byte = row_base + 256 + sct * 64 + q * 16;
        *(s16x8*)((char*)Alds + (byte ^ ((sr & 7) << 4))) = hv;
      }
    }
    // issue x_{t+1} prefetch (in flight during GEMM)
    f32x4 vx0, vx1;
    if (t < S_ - 1) {
      const float* xp = x + ((size_t)b_st * S_ + (t + 1)) * D_ + sct * 8;
      vx0 = *(const f32x4*)xp;
      vx1 = *(const f32x4*)(xp + 4);
    }
    __syncthreads();

    // ---- GEMM: wave computes 16 rows x 32 cols, K=640 ----
    f32x4 acc0 = {0.f, 0.f, 0.f, 0.f};
    f32x4 acc1 = {0.f, 0.f, 0.f, 0.f};
    #pragma unroll
    for (int kk = 0; kk < 20; ++kk) {
      unsigned byte = (unsigned)(ar * (K_ * 2) + kk * 64 + ahi * 16);
      s16x8 af = *(const s16x8*)((const char*)Alds + (byte ^ ((ar & 7) << 4)));
      acc0 = __builtin_amdgcn_mfma_f32_16x16x32_bf16(af, bfrag0[kk], acc0, 0, 0, 0);
      acc1 = __builtin_amdgcn_mfma_f32_16x16x32_bf16(af, bfrag1[kk], acc1, 0, 0, 0);
    }

    // ---- scatter gates to LDS (C/D layout: col=lane&15, row=(lane>>4)*4+reg) ----
    {
      const int row0 = (lane >> 4) * 4;
      const int dc = lane & 15;
      #pragma unroll
      for (int g = 0; g < 4; ++g) {
        gate_lds[wv][row0 + g][dc]      = acc0[g];
        gate_lds[wv][row0 + g][16 + dc] = acc1[g];
      }
    }
    __syncthreads();   // gate_lds ready; everyone done reading Alds

    // ---- cell update: 2 consecutive (b,j) pairs -> 8 consecutive gate floats ----
    {
      f32x4 gA = *(const f32x4*)&gate_lds[wv][r_own][jl_own * 4];
      f32x4 gB = *(const f32x4*)&gate_lds[wv][r_own][jl_own * 4 + 4];
      const float* bl = &bias_lds[wv * 32 + jl_own * 4];
      float c0n = sigm(gA[1] + bl[1]) * c_reg[0] + sigm(gA[0] + bl[0]) * tanh_(gA[2] + bl[2]);
      float c1n = sigm(gB[1] + bl[5]) * c_reg[1] + sigm(gB[0] + bl[4]) * tanh_(gB[2] + bl[6]);
      c_reg[0] = c0n; c_reg[1] = c1n;
      float h0n = sigm(gA[3] + bl[3]) * tanh_(c0n);
      float h1n = sigm(gB[3] + bl[7]) * tanh_(c1n);
      pool_acc[0] += h0n; pool_acc[1] += h1n;
      unsigned packed = (unsigned)f2bf(h0n) | ((unsigned)f2bf(h1n) << 16);
      *(unsigned*)(hout + (size_t)b_own * H2_ + j_own) = packed;
    }

    if (t < S_ - 1) {
      // ---- group barrier: arrive ----
      __threadfence();          // release: h stores drained to L2 (agent scope)
      __syncthreads();          // all 256 threads have fenced
      if (tid == 0)
        __hip_atomic_fetch_add(my_cnt, 1u, __ATOMIC_RELAXED, __HIP_MEMORY_SCOPE_AGENT);

      // ---- overlap: write x_{t+1} into A-tile x-part (GEMM done by all waves) ----
      {
        s16x8 pk;
        pk[0] = (short)f2bf(vx0[0]); pk[1] = (short)f2bf(vx0[1]);
        pk[2] = (short)f2bf(vx0[2]); pk[3] = (short)f2bf(vx0[3]);
        pk[4] = (short)f2bf(vx1[0]); pk[5] = (short)f2bf(vx1[1]);
        pk[6] = (short)f2bf(vx1[2]); pk[7] = (short)f2bf(vx1[3]);
        *(s16x8*)((char*)Alds + swz_x) = pk;
      }

      // ---- group barrier: wait ----
      if (tid == 0) {
        const unsigned target = 16u * (unsigned)(t + 1);
        while (__hip_atomic_load(my_cnt, __ATOMIC_RELAXED, __HIP_MEMORY_SCOPE_AGENT) < target)
          __builtin_amdgcn_s_sleep(1);
      }
      __syncthreads();
      __threadfence();          // acquire: invalidate L1 so next h reads are fresh
    }
  }

  *(f32x2*)(pooled + (size_t)b_own * H2_ + j_own) = pool_acc;
}

// ---------------- fused fc1(relu)+fc2 per batch row -------------------------
__global__ void fc_kernel(const float* __restrict__ pooled,
                          const float* __restrict__ fc1_w, const float* __restrict__ fc1_b,
                          const float* __restrict__ fc2_w, const float* __restrict__ fc2_b,
                          float* __restrict__ out) {
  const int b = blockIdx.x;
  const int tid = threadIdx.x;   // 256
  __shared__ float prow[H2_];
  __shared__ float dec[H2_];
  __shared__ float red[256];
  prow[tid]       = pooled[(size_t)b * H2_ + tid];
  prow[tid + 256] = pooled[(size_t)b * H2_ + tid + 256];
  __syncthreads();
  #pragma unroll
  for (int e = 0; e < 2; ++e) {
    const int o = tid + e * 256;
    const float* wrow = fc1_w + (size_t)o * H2_;
    float a = fc1_b[o];
    #pragma unroll 8
    for (int k = 0; k < H2_; ++k) a += prow[k] * wrow[k];
    dec[o] = fmaxf(a, 0.f);
  }
  __syncthreads();
  red[tid] = dec[tid] * fc2_w[tid] + dec[tid + 256] * fc2_w[tid + 256];
  __syncthreads();
  for (int s = 128; s > 0; s >>= 1) {
    if (tid < s) red[tid] += red[tid + s];
    __syncthreads();
  }
  if (tid == 0) out[b] = red[0] + fc2_b[0];
}

// ---------------- launch -----------------------------------------------------
extern "C" void kernel_launch(void* const* d_in, const int* in_sizes, int n_in,
                              void* d_out, int out_size, void* d_ws, size_t ws_size,
                              hipStream_t stream) {
  const float* x      = (const float*)d_in[0];
  const float* conv_w = (const float*)d_in[1];
  const float* conv_b = (const float*)d_in[2];
  const float* w_ih   = (const float*)d_in[3];
  const float* b_ih   = (const float*)d_in[4];
  const float* w_hh   = (const float*)d_in[5];
  const float* b_hh   = (const float*)d_in[6];
  const float* h0     = (const float*)d_in[7];
  const float* c0     = (const float*)d_in[8];
  const float* fc1_w  = (const float*)d_in[9];
  const float* fc1_b  = (const float*)d_in[10];
  const float* fc2_w  = (const float*)d_in[11];
  const float* fc2_b  = (const float*)d_in[12];
  float* out = (float*)d_out;

  char* ws = (char*)d_ws;
  // ws layout (bytes):
  //   Wc     [2048][640] bf16 : 0        .. 2621440
  //   bias   [2048]      f32  : 2621440  .. 2629632
  //   h_bf [2][256][512] bf16 : 2629632  .. 3153920
  //   pooled [256][512]  f32  : 3153920  .. 3678208
  //   barrier_cnt 16x128B u32 : 3678208  .. 3680256
  unsigned short* Wc    = (unsigned short*)(ws);
  float* bias           = (float*)(ws + 2621440);
  unsigned short* h_bf  = (unsigned short*)(ws + 2629632);
  float* pooled         = (float*)(ws + 3153920);
  unsigned* barrier_cnt = (unsigned*)(ws + 3678208);

  prep_kernel<<<dim3(G4_), dim3(128), 0, stream>>>(conv_w, conv_b, w_ih, b_ih,
                                                   w_hh, b_hh, Wc, bias, barrier_cnt);

  void* args[8];
  args[0] = (void*)&x;    args[1] = (void*)&h0;   args[2] = (void*)&c0;
  args[3] = (void*)&Wc;   args[4] = (void*)&bias; args[5] = (void*)&h_bf;
  args[6] = (void*)&pooled; args[7] = (void*)&barrier_cnt;
  hipLaunchCooperativeKernel((void*)lstm_kernel, dim3(256), dim3(256), args, 0, stream);

  fc_kernel<<<dim3(B_), dim3(256), 0, stream>>>(pooled, fc1_w, fc1_b, fc2_w, fc2_b, out);
}

// Round 7
// 1914.179 us; speedup vs baseline: 9.9630x; 9.9630x over previous
//
#include <hip/hip_runtime.h>
#include <hip/hip_cooperative_groups.h>

// PN_Critic: conv1d(k=1) -> 512-step LSTM -> time-sum -> fc1(relu) -> fc2
// B=256 S=512 D=128 H1=256 H2=512, gates=2048, combined K = 128+512 = 640.
//
// Round-4 theory: rounds 2/3 were ~36us/step with MfmaUtil 0.7% because every
// step ran >=2 agent-scope fences (grid.sync / __threadfence), each sweeping
// the per-XCD L2 (buffer_wbl2/buffer_inv ~13-17us). This version has ZERO
// per-step fences:
//  * h exchange + flags use sc0|sc1 (device-coherent, cache-bypass) loads and
//    stores -> point-to-point through the coherence point, no L2 sweeps.
//  * release ordering = s_waitcnt vmcnt(0) between h stores and flag store.
//  * barrier = monotonic flag per (group, producer WG) + 16-lane parallel poll.
//  * swapped-operand MFMA (D = Wc_tile . A^T -> D[n'][b]): with gate
//    interleave n'=4j+g, each lane's 4 acc regs are exactly (i,f,g,o) of one
//    (b,j) -> cell update fully in-register; gate_lds scatter (the 1.0e8 bank
//    conflict source) and one __syncthreads deleted.
//  * t=0 stages h from h0 directly -> no init pass, no grid.sync anywhere.

typedef __attribute__((ext_vector_type(8))) short s16x8;
typedef __attribute__((ext_vector_type(4))) float f32x4;

#define B_   256
#define S_   512
#define D_   128
#define H1_  256
#define H2_  512
#define G4_  2048
#define K_   640

__device__ __forceinline__ unsigned short f2bf(float f) {
  union { float f; unsigned u; } v; v.f = f;
  unsigned r = v.u + 0x7FFFu + ((v.u >> 16) & 1u);   // round-nearest-even
  return (unsigned short)(r >> 16);
}
__device__ __forceinline__ float sigm(float x) { return 1.f / (1.f + __expf(-x)); }
__device__ __forceinline__ float tanh_(float x) { return 1.f - 2.f / (__expf(2.f * x) + 1.f); }

// ---- device-coherent (cross-XCD, fence-free) memory ops: sc0|sc1 ----------
__device__ __forceinline__ s16x8 ld_cohx8(const unsigned short* p) {
  s16x8 d;
  asm volatile("global_load_dwordx4 %0, %1, off sc0 sc1" : "=v"(d) : "v"(p));
  return d;
}
__device__ __forceinline__ void st_coh_u16(unsigned short* p, unsigned v) {
  asm volatile("global_store_short %0, %1, off sc0 sc1" :: "v"(p), "v"(v) : "memory");
}
__device__ __forceinline__ void st_coh_u32(unsigned* p, unsigned v) {
  asm volatile("global_store_dword %0, %1, off sc0 sc1" :: "v"(p), "v"(v) : "memory");
}
__device__ __forceinline__ unsigned ld_coh_u32(const unsigned* p) {
  unsigned d;
  asm volatile("global_load_dword %0, %1, off sc0 sc1\n\ts_waitcnt vmcnt(0)"
               : "=v"(d) : "v"(p) : "memory");
  return d;
}
__device__ __forceinline__ void vm_drain() {
  asm volatile("s_waitcnt vmcnt(0)" ::: "memory");
  __builtin_amdgcn_sched_barrier(0);
}

// ---------------- prep: build combined weight + bias (gate-interleaved rows) --
__global__ void prep_kernel(const float* __restrict__ conv_w, const float* __restrict__ conv_b,
                            const float* __restrict__ w_ih,   const float* __restrict__ b_ih,
                            const float* __restrict__ w_hh,   const float* __restrict__ b_hh,
                            unsigned short* __restrict__ Wc,  float* __restrict__ bias,
                            unsigned* __restrict__ flags) {
  const int np = blockIdx.x;          // n' = 4*j + g
  const int g = np & 3, j = np >> 2;
  const int n = g * H2_ + j;          // original gate row
  const int tid = threadIdx.x;        // 128 threads

  if (np == 0) { flags[tid] = 0; flags[tid + 128] = 0; }  // zero 256 flags

  __shared__ float wrow[H1_];
  __shared__ float red[128];
  wrow[tid]       = w_ih[(size_t)n * H1_ + tid];
  wrow[tid + 128] = w_ih[(size_t)n * H1_ + tid + 128];
  __syncthreads();

  // x-projection part: k = tid (0..127)
  float acc = 0.f;
  for (int h1 = 0; h1 < H1_; ++h1)
    acc += wrow[h1] * conv_w[(size_t)h1 * D_ + tid];
  Wc[(size_t)np * K_ + tid] = f2bf(acc);

  // recurrent part: copy w_hh row (bf16)
  #pragma unroll
  for (int r = 0; r < 4; ++r)
    Wc[(size_t)np * K_ + 128 + tid + r * 128] = f2bf(w_hh[(size_t)n * H2_ + tid + r * 128]);

  // bias[n'] = b_ih + b_hh + w_ih@conv_b
  float p = wrow[tid] * conv_b[tid] + wrow[tid + 128] * conv_b[tid + 128];
  red[tid] = p;
  __syncthreads();
  for (int s = 64; s > 0; s >>= 1) {
    if (tid < s) red[tid] += red[tid + s];
    __syncthreads();
  }
  if (tid == 0) bias[np] = red[0] + b_ih[n] + b_hh[n];
}

// ---------------- persistent LSTM (fence-free exchange) ---------------------
__global__ __launch_bounds__(256, 1) void lstm_kernel(
    const float* __restrict__ x, const float* __restrict__ h0,
    const float* __restrict__ c0, const unsigned short* __restrict__ Wc,
    const float* __restrict__ bias, unsigned short* __restrict__ h_bf,
    float* __restrict__ pooled, unsigned* __restrict__ flags) {
  const int wg = blockIdx.x;       // 256 WGs = 16 mg x 16 ng
  const int mg = wg & 15;          // batch rows mg*16 .. +16
  const int ng = wg >> 4;          // gate cols ng*128 .. +128
  const int tid = threadIdx.x;
  const int wv = tid >> 6;         // wave 0..3: cols wv*32 within the 128
  const int lane = tid & 63;

  __shared__ unsigned short Alds[16 * K_];   // XOR-swizzled, 1280 B/row

  // --- Wc fragments (A-operand of swapped MFMA): lane holds Wc[n0+(lane&15)][k-slice]
  const int n0 = ng * 128 + wv * 32;
  s16x8 bfrag0[20], bfrag1[20];
  {
    const int bn0 = n0 + (lane & 15);
    const int bk = (lane >> 4) * 8;
    #pragma unroll
    for (int kk = 0; kk < 20; ++kk) {
      bfrag0[kk] = *(const s16x8*)(Wc + (size_t)bn0 * K_ + kk * 32 + bk);
      bfrag1[kk] = *(const s16x8*)(Wc + (size_t)(bn0 + 16) * K_ + kk * 32 + bk);
    }
  }
  #pragma unroll
  for (int kk = 0; kk < 20; ++kk)
    asm volatile("" : "+v"(bfrag0[kk]), "+v"(bfrag1[kk]));

  // --- ownership from swapped-MFMA D layout: row n' = (lane>>4)*4+g, col b = lane&15
  const int b_own = mg * 16 + (lane & 15);
  const int j0 = ng * 32 + wv * 8 + (lane >> 4);   // acc0 regs g=0..3 = gates of j0
  const int j1 = j0 + 4;                           // acc1 -> j1
  const f32x4 brg0 = *(const f32x4*)(bias + 4 * j0);
  const f32x4 brg1 = *(const f32x4*)(bias + 4 * j1);
  float cA = c0[(size_t)b_own * H2_ + j0];
  float cB = c0[(size_t)b_own * H2_ + j1];
  float poolA = 0.f, poolB = 0.f;

  // staging geometry: 16 rows x 16 col-threads
  const int sr = tid >> 4, sct = tid & 15;
  const int b_st = mg * 16 + sr;
  const unsigned row_base = sr * (K_ * 2);
  const unsigned swz = (unsigned)((sr & 7) << 4);
  const unsigned swz_x = (row_base + sct * 16) ^ swz;

  const int ar = lane & 15;                  // A-tile row (batch) for GEMM read
  const int ahi = lane >> 4;                 // k-slice selector
  unsigned* fgrp = flags + mg * 16;

  // prologue: stage x_0
  {
    const float* xp = x + ((size_t)b_st * S_) * D_ + sct * 8;
    f32x4 v0 = *(const f32x4*)xp;
    f32x4 v1 = *(const f32x4*)(xp + 4);
    s16x8 pk;
    pk[0] = (short)f2bf(v0[0]); pk[1] = (short)f2bf(v0[1]);
    pk[2] = (short)f2bf(v0[2]); pk[3] = (short)f2bf(v0[3]);
    pk[4] = (short)f2bf(v1[0]); pk[5] = (short)f2bf(v1[1]);
    pk[6] = (short)f2bf(v1[2]); pk[7] = (short)f2bf(v1[3]);
    *(s16x8*)((char*)Alds + swz_x) = pk;
  }

  #pragma unroll 1
  for (int t = 0; t < S_; ++t) {
    unsigned short* hout = h_bf + ((t + 1) & 1) * (B_ * H2_);

    // ---- stage h-input rows into LDS (swizzled) ----
    if (t == 0) {
      const float* hp = h0 + (size_t)b_st * H2_ + sct * 32;
      #pragma unroll
      for (int q = 0; q < 4; ++q) {
        f32x4 a = *(const f32x4*)(hp + q * 8);
        f32x4 b = *(const f32x4*)(hp + q * 8 + 4);
        s16x8 pk;
        pk[0] = (short)f2bf(a[0]); pk[1] = (short)f2bf(a[1]);
        pk[2] = (short)f2bf(a[2]); pk[3] = (short)f2bf(a[3]);
        pk[4] = (short)f2bf(b[0]); pk[5] = (short)f2bf(b[1]);
        pk[6] = (short)f2bf(b[2]); pk[7] = (short)f2bf(b[3]);
        unsigned byte = row_base + 256 + sct * 64 + q * 16;
        *(s16x8*)((char*)Alds + (byte ^ swz)) = pk;
      }
    } else {
      const unsigned short* hin = h_bf + (t & 1) * (B_ * H2_);
      const unsigned short* hrow = hin + (size_t)b_st * H2_ + sct * 32;
      s16x8 hv0 = ld_cohx8(hrow);
      s16x8 hv1 = ld_cohx8(hrow + 8);
      s16x8 hv2 = ld_cohx8(hrow + 16);
      s16x8 hv3 = ld_cohx8(hrow + 24);
      vm_drain();
      unsigned byte = row_base + 256 + sct * 64;
      *(s16x8*)((char*)Alds + ((byte     ) ^ swz)) = hv0;
      *(s16x8*)((char*)Alds + ((byte + 16) ^ swz)) = hv1;
      *(s16x8*)((char*)Alds + ((byte + 32) ^ swz)) = hv2;
      *(s16x8*)((char*)Alds + ((byte + 48) ^ swz)) = hv3;
    }
    // issue x_{t+1} loads (consumed after GEMM)
    f32x4 vx0, vx1;
    if (t < S_ - 1) {
      const float* xp = x + ((size_t)b_st * S_ + (t + 1)) * D_ + sct * 8;
      vx0 = *(const f32x4*)xp;
      vx1 = *(const f32x4*)(xp + 4);
    }
    __syncthreads();   // #A: A-tile ready

    // ---- GEMM (swapped): D[n'][b] ; wave does 32 n' x 16 b, K=640 ----
    f32x4 acc0 = {0.f, 0.f, 0.f, 0.f};
    f32x4 acc1 = {0.f, 0.f, 0.f, 0.f};
    #pragma unroll
    for (int kk = 0; kk < 20; ++kk) {
      unsigned byte = (unsigned)(ar * (K_ * 2) + kk * 64 + ahi * 16);
      s16x8 af = *(const s16x8*)((const char*)Alds + (byte ^ ((ar & 7) << 4)));
      acc0 = __builtin_amdgcn_mfma_f32_16x16x32_bf16(bfrag0[kk], af, acc0, 0, 0, 0);
      acc1 = __builtin_amdgcn_mfma_f32_16x16x32_bf16(bfrag1[kk], af, acc1, 0, 0, 0);
    }

    // ---- cell update: fully in-register (lane owns (b_own, j0) and (b_own, j1)) ----
    {
      float iA = sigm(acc0[0] + brg0[0]);
      float fA = sigm(acc0[1] + brg0[1]);
      float gA = tanh_(acc0[2] + brg0[2]);
      float oA = sigm(acc0[3] + brg0[3]);
      cA = fA * cA + iA * gA;
      float hA = oA * tanh_(cA);
      poolA += hA;
      float iB = sigm(acc1[0] + brg1[0]);
      float fB = sigm(acc1[1] + brg1[1]);
      float gB = tanh_(acc1[2] + brg1[2]);
      float oB = sigm(acc1[3] + brg1[3]);
      cB = fB * cB + iB * gB;
      float hB = oB * tanh_(cB);
      poolB += hB;
      if (t < S_ - 1) {
        st_coh_u16(hout + (size_t)b_own * H2_ + j0, (unsigned)f2bf(hA));
        st_coh_u16(hout + (size_t)b_own * H2_ + j1, (unsigned)f2bf(hB));
      }
    }

    if (t < S_ - 1) {
      vm_drain();          // release: h stores at coherence point (also drains vx)
      __syncthreads();     // #B: all waves drained; all GEMM reads of Alds done
      if (tid == 0) st_coh_u32(fgrp + ng, (unsigned)(t + 1));

      // overlap: write x_{t+1} into A-tile x-part
      {
        s16x8 pk;
        pk[0] = (short)f2bf(vx0[0]); pk[1] = (short)f2bf(vx0[1]);
        pk[2] = (short)f2bf(vx0[2]); pk[3] = (short)f2bf(vx0[3]);
        pk[4] = (short)f2bf(vx1[0]); pk[5] = (short)f2bf(vx1[1]);
        pk[6] = (short)f2bf(vx1[2]); pk[7] = (short)f2bf(vx1[3]);
        *(s16x8*)((char*)Alds + swz_x) = pk;
      }

      // wait: every wave polls the 16 group flags (lanes share one 64B line)
      const unsigned tgt = (unsigned)(t + 1);
      const unsigned* fp = fgrp + (lane & 15);
      while (!__all(ld_coh_u32(fp) >= tgt))
        __builtin_amdgcn_s_sleep(1);
      // next stage-h writes are per-thread-disjoint LDS slots; sync #A orders
      // them against the next GEMM.
    }
  }

  pooled[(size_t)b_own * H2_ + j0] = poolA;
  pooled[(size_t)b_own * H2_ + j1] = poolB;
}

// ---------------- fused fc1(relu)+fc2 per batch row -------------------------
__global__ void fc_kernel(const float* __restrict__ pooled,
                          const float* __restrict__ fc1_w, const float* __restrict__ fc1_b,
                          const float* __restrict__ fc2_w, const float* __restrict__ fc2_b,
                          float* __restrict__ out) {
  const int b = blockIdx.x;
  const int tid = threadIdx.x;   // 256
  __shared__ float prow[H2_];
  __shared__ float dec[H2_];
  __shared__ float red[256];
  prow[tid]       = pooled[(size_t)b * H2_ + tid];
  prow[tid + 256] = pooled[(size_t)b * H2_ + tid + 256];
  __syncthreads();
  #pragma unroll
  for (int e = 0; e < 2; ++e) {
    const int o = tid + e * 256;
    const float* wrow = fc1_w + (size_t)o * H2_;
    float a = fc1_b[o];
    #pragma unroll 8
    for (int k = 0; k < H2_; ++k) a += prow[k] * wrow[k];
    dec[o] = fmaxf(a, 0.f);
  }
  __syncthreads();
  red[tid] = dec[tid] * fc2_w[tid] + dec[tid + 256] * fc2_w[tid + 256];
  __syncthreads();
  for (int s = 128; s > 0; s >>= 1) {
    if (tid < s) red[tid] += red[tid + s];
    __syncthreads();
  }
  if (tid == 0) out[b] = red[0] + fc2_b[0];
}

// ---------------- launch -----------------------------------------------------
extern "C" void kernel_launch(void* const* d_in, const int* in_sizes, int n_in,
                              void* d_out, int out_size, void* d_ws, size_t ws_size,
                              hipStream_t stream) {
  const float* x      = (const float*)d_in[0];
  const float* conv_w = (const float*)d_in[1];
  const float* conv_b = (const float*)d_in[2];
  const float* w_ih   = (const float*)d_in[3];
  const float* b_ih   = (const float*)d_in[4];
  const float* w_hh   = (const float*)d_in[5];
  const float* b_hh   = (const float*)d_in[6];
  const float* h0     = (const float*)d_in[7];
  const float* c0     = (const float*)d_in[8];
  const float* fc1_w  = (const float*)d_in[9];
  const float* fc1_b  = (const float*)d_in[10];
  const float* fc2_w  = (const float*)d_in[11];
  const float* fc2_b  = (const float*)d_in[12];
  float* out = (float*)d_out;

  char* ws = (char*)d_ws;
  // ws layout (bytes):
  //   Wc     [2048][640] bf16 : 0        .. 2621440
  //   bias   [2048]      f32  : 2621440  .. 2629632
  //   h_bf [2][256][512] bf16 : 2629632  .. 3153920
  //   pooled [256][512]  f32  : 3153920  .. 3678208
  //   flags  [16][16]    u32  : 3678208  .. 3679232
  unsigned short* Wc    = (unsigned short*)(ws);
  float* bias           = (float*)(ws + 2621440);
  unsigned short* h_bf  = (unsigned short*)(ws + 2629632);
  float* pooled         = (float*)(ws + 3153920);
  unsigned* flags       = (unsigned*)(ws + 3678208);

  prep_kernel<<<dim3(G4_), dim3(128), 0, stream>>>(conv_w, conv_b, w_ih, b_ih,
                                                   w_hh, b_hh, Wc, bias, flags);

  void* args[8];
  args[0] = (void*)&x;    args[1] = (void*)&h0;   args[2] = (void*)&c0;
  args[3] = (void*)&Wc;   args[4] = (void*)&bias; args[5] = (void*)&h_bf;
  args[6] = (void*)&pooled; args[7] = (void*)&flags;
  hipLaunchCooperativeKernel((void*)lstm_kernel, dim3(256), dim3(256), args, 0, stream);

  fc_kernel<<<dim3(B_), dim3(256), 0, stream>>>(pooled, fc1_w, fc1_b, fc2_w, fc2_b, out);
}

// Round 9
// 1784.134 us; speedup vs baseline: 10.6892x; 1.0729x over previous
//
#include <hip/hip_runtime.h>
#include <hip/hip_cooperative_groups.h>

// PN_Critic: conv1d(k=1) -> 512-step LSTM -> time-sum -> fc1(relu) -> fc2
// B=256 S=512 D=128 H1=256 H2=512, gates=2048, combined K = 128+512 = 640.
//
// Round-8 (on top of the round-7 fence-free design, 1914us measured):
//  * vx prefetch converted to bf16 regs BEFORE the release drain -> the
//    vm_drain before flag publish now waits ONLY the packed h store
//    (round 7 stacked a ~900cyc HBM load wait onto every step).
//  * adjacent-j ownership: Wc rows permuted in prep (storage row
//    32c+16blk+4q+g <-> j = 8c+2q+blk) so each lane owns (j0, j0+1):
//    h store = ONE packed u32 (was 2 scattered u16 -> halves write-through
//    transactions; round-7 WRITE_SIZE was 528MB vs 128MB logical),
//    c0/pooled become f32x2.
//  * x-LDS write moved after sync #B (pure LDS, off the drain path).

typedef __attribute__((ext_vector_type(8))) short s16x8;
typedef __attribute__((ext_vector_type(4))) float f32x4;
typedef __attribute__((ext_vector_type(2))) float f32x2;

#define B_   256
#define S_   512
#define D_   128
#define H1_  256
#define H2_  512
#define G4_  2048
#define K_   640

__device__ __forceinline__ unsigned short f2bf(float f) {
  union { float f; unsigned u; } v; v.f = f;
  unsigned r = v.u + 0x7FFFu + ((v.u >> 16) & 1u);   // round-nearest-even
  return (unsigned short)(r >> 16);
}
__device__ __forceinline__ float sigm(float x) { return 1.f / (1.f + __expf(-x)); }
__device__ __forceinline__ float tanh_(float x) { return 1.f - 2.f / (__expf(2.f * x) + 1.f); }

// ---- device-coherent (cross-XCD, fence-free) memory ops: sc0|sc1 ----------
__device__ __forceinline__ s16x8 ld_cohx8(const unsigned short* p) {
  s16x8 d;
  asm volatile("global_load_dwordx4 %0, %1, off sc0 sc1" : "=v"(d) : "v"(p));
  return d;
}
__device__ __forceinline__ void st_coh_u32(unsigned* p, unsigned v) {
  asm volatile("global_store_dword %0, %1, off sc0 sc1" :: "v"(p), "v"(v) : "memory");
}
__device__ __forceinline__ unsigned ld_coh_u32(const unsigned* p) {
  unsigned d;
  asm volatile("global_load_dword %0, %1, off sc0 sc1\n\ts_waitcnt vmcnt(0)"
               : "=v"(d) : "v"(p) : "memory");
  return d;
}
__device__ __forceinline__ void vm_drain() {
  asm volatile("s_waitcnt vmcnt(0)" ::: "memory");
  __builtin_amdgcn_sched_barrier(0);
}

// ---------------- prep: combined weight + bias, permuted-interleaved rows ---
// storage row np = 32c + 16blk + 4q + g  <->  original n = g*512 + j,
// j = 8c + 2q + blk.  bias kept canonical: bias[4j+g].
__global__ void prep_kernel(const float* __restrict__ conv_w, const float* __restrict__ conv_b,
                            const float* __restrict__ w_ih,   const float* __restrict__ b_ih,
                            const float* __restrict__ w_hh,   const float* __restrict__ b_hh,
                            unsigned short* __restrict__ Wc,  float* __restrict__ bias,
                            unsigned* __restrict__ flags) {
  const int np = blockIdx.x;          // storage row
  const int c = np >> 5, r5 = np & 31;
  const int blk = r5 >> 4, q = (r5 >> 2) & 3, g = r5 & 3;
  const int j = c * 8 + 2 * q + blk;
  const int n = g * H2_ + j;          // original gate row
  const int tid = threadIdx.x;        // 128 threads

  if (np == 0) { flags[tid] = 0; flags[tid + 128] = 0; }  // zero 256 flags

  __shared__ float wrow[H1_];
  __shared__ float red[128];
  wrow[tid]       = w_ih[(size_t)n * H1_ + tid];
  wrow[tid + 128] = w_ih[(size_t)n * H1_ + tid + 128];
  __syncthreads();

  // x-projection part: k = tid (0..127)
  float acc = 0.f;
  for (int h1 = 0; h1 < H1_; ++h1)
    acc += wrow[h1] * conv_w[(size_t)h1 * D_ + tid];
  Wc[(size_t)np * K_ + tid] = f2bf(acc);

  // recurrent part: copy w_hh row (bf16)
  #pragma unroll
  for (int r = 0; r < 4; ++r)
    Wc[(size_t)np * K_ + 128 + tid + r * 128] = f2bf(w_hh[(size_t)n * H2_ + tid + r * 128]);

  // bias[4j+g] = b_ih + b_hh + w_ih@conv_b
  float p = wrow[tid] * conv_b[tid] + wrow[tid + 128] * conv_b[tid + 128];
  red[tid] = p;
  __syncthreads();
  for (int s = 64; s > 0; s >>= 1) {
    if (tid < s) red[tid] += red[tid + s];
    __syncthreads();
  }
  if (tid == 0) bias[4 * j + g] = red[0] + b_ih[n] + b_hh[n];
}

// ---------------- persistent LSTM (fence-free exchange) ---------------------
__global__ __launch_bounds__(256, 1) void lstm_kernel(
    const float* __restrict__ x, const float* __restrict__ h0,
    const float* __restrict__ c0, const unsigned short* __restrict__ Wc,
    const float* __restrict__ bias, unsigned short* __restrict__ h_bf,
    float* __restrict__ pooled, unsigned* __restrict__ flags) {
  const int wg = blockIdx.x;       // 256 WGs = 16 mg x 16 ng
  const int mg = wg & 15;          // batch rows mg*16 .. +16
  const int ng = wg >> 4;          // gate cols ng*128 .. +128
  const int tid = threadIdx.x;
  const int wv = tid >> 6;         // wave 0..3
  const int lane = tid & 63;

  __shared__ unsigned short Alds[16 * K_];   // XOR-swizzled, 1280 B/row

  // --- Wc fragments (A-operand of swapped MFMA) ---
  const int n0 = ng * 128 + wv * 32;
  s16x8 bfrag0[20], bfrag1[20];
  {
    const int bn0 = n0 + (lane & 15);
    const int bk = (lane >> 4) * 8;
    #pragma unroll
    for (int kk = 0; kk < 20; ++kk) {
      bfrag0[kk] = *(const s16x8*)(Wc + (size_t)bn0 * K_ + kk * 32 + bk);
      bfrag1[kk] = *(const s16x8*)(Wc + (size_t)(bn0 + 16) * K_ + kk * 32 + bk);
    }
  }
  #pragma unroll
  for (int kk = 0; kk < 20; ++kk)
    asm volatile("" : "+v"(bfrag0[kk]), "+v"(bfrag1[kk]));

  // --- ownership: lane -> (b_own, j0) and (b_own, j0+1)  [adjacent!] ---
  const int b_own = mg * 16 + (lane & 15);
  const int j0 = ng * 32 + wv * 8 + 2 * (lane >> 4);   // even
  const f32x4 brg0 = *(const f32x4*)(bias + 4 * j0);         // gates of j0
  const f32x4 brg1 = *(const f32x4*)(bias + 4 * (j0 + 1));   // gates of j0+1
  f32x2 c_reg = *(const f32x2*)(c0 + (size_t)b_own * H2_ + j0);
  f32x2 pool_acc = {0.f, 0.f};

  // staging geometry: 16 rows x 16 col-threads
  const int sr = tid >> 4, sct = tid & 15;
  const int b_st = mg * 16 + sr;
  const unsigned row_base = sr * (K_ * 2);
  const unsigned swz = (unsigned)((sr & 7) << 4);
  const unsigned swz_x = (row_base + sct * 16) ^ swz;

  const int ar = lane & 15;                  // A-tile row (batch) for GEMM read
  const int ahi = lane >> 4;                 // k-slice selector
  unsigned* fgrp = flags + mg * 16;

  // prologue: stage x_0
  {
    const float* xp = x + ((size_t)b_st * S_) * D_ + sct * 8;
    f32x4 v0 = *(const f32x4*)xp;
    f32x4 v1 = *(const f32x4*)(xp + 4);
    s16x8 pk;
    pk[0] = (short)f2bf(v0[0]); pk[1] = (short)f2bf(v0[1]);
    pk[2] = (short)f2bf(v0[2]); pk[3] = (short)f2bf(v0[3]);
    pk[4] = (short)f2bf(v1[0]); pk[5] = (short)f2bf(v1[1]);
    pk[6] = (short)f2bf(v1[2]); pk[7] = (short)f2bf(v1[3]);
    *(s16x8*)((char*)Alds + swz_x) = pk;
  }

  #pragma unroll 1
  for (int t = 0; t < S_; ++t) {
    unsigned short* hout = h_bf + ((t + 1) & 1) * (B_ * H2_);

    // ---- stage h-input rows into LDS (swizzled) ----
    if (t == 0) {
      const float* hp = h0 + (size_t)b_st * H2_ + sct * 32;
      #pragma unroll
      for (int q = 0; q < 4; ++q) {
        f32x4 a = *(const f32x4*)(hp + q * 8);
        f32x4 b = *(const f32x4*)(hp + q * 8 + 4);
        s16x8 pk;
        pk[0] = (short)f2bf(a[0]); pk[1] = (short)f2bf(a[1]);
        pk[2] = (short)f2bf(a[2]); pk[3] = (short)f2bf(a[3]);
        pk[4] = (short)f2bf(b[0]); pk[5] = (short)f2bf(b[1]);
        pk[6] = (short)f2bf(b[2]); pk[7] = (short)f2bf(b[3]);
        unsigned byte = row_base + 256 + sct * 64 + q * 16;
        *(s16x8*)((char*)Alds + (byte ^ swz)) = pk;
      }
    } else {
      const unsigned short* hin = h_bf + (t & 1) * (B_ * H2_);
      const unsigned short* hrow = hin + (size_t)b_st * H2_ + sct * 32;
      s16x8 hv0 = ld_cohx8(hrow);
      s16x8 hv1 = ld_cohx8(hrow + 8);
      s16x8 hv2 = ld_cohx8(hrow + 16);
      s16x8 hv3 = ld_cohx8(hrow + 24);
      vm_drain();
      unsigned byte = row_base + 256 + sct * 64;
      *(s16x8*)((char*)Alds + ((byte     ) ^ swz)) = hv0;
      *(s16x8*)((char*)Alds + ((byte + 16) ^ swz)) = hv1;
      *(s16x8*)((char*)Alds + ((byte + 32) ^ swz)) = hv2;
      *(s16x8*)((char*)Alds + ((byte + 48) ^ swz)) = hv3;
    }
    // issue x_{t+1} loads (in flight across the GEMM; consumed pre-drain)
    f32x4 vx0, vx1;
    if (t < S_ - 1) {
      const float* xp = x + ((size_t)b_st * S_ + (t + 1)) * D_ + sct * 8;
      vx0 = *(const f32x4*)xp;
      vx1 = *(const f32x4*)(xp + 4);
    }
    __syncthreads();   // #A: A-tile ready

    // ---- GEMM (swapped): D[n'][b] ; wave does 32 n' x 16 b, K=640 ----
    f32x4 acc0 = {0.f, 0.f, 0.f, 0.f};
    f32x4 acc1 = {0.f, 0.f, 0.f, 0.f};
    #pragma unroll
    for (int kk = 0; kk < 20; ++kk) {
      unsigned byte = (unsigned)(ar * (K_ * 2) + kk * 64 + ahi * 16);
      s16x8 af = *(const s16x8*)((const char*)Alds + (byte ^ ((ar & 7) << 4)));
      acc0 = __builtin_amdgcn_mfma_f32_16x16x32_bf16(bfrag0[kk], af, acc0, 0, 0, 0);
      acc1 = __builtin_amdgcn_mfma_f32_16x16x32_bf16(bfrag1[kk], af, acc1, 0, 0, 0);
    }

    // ---- cell update: in-register; packed u32 h store (j0, j0+1) ----
    {
      float iA = sigm(acc0[0] + brg0[0]);
      float fA = sigm(acc0[1] + brg0[1]);
      float gA = tanh_(acc0[2] + brg0[2]);
      float oA = sigm(acc0[3] + brg0[3]);
      c_reg[0] = fA * c_reg[0] + iA * gA;
      float hA = oA * tanh_(c_reg[0]);
      pool_acc[0] += hA;
      float iB = sigm(acc1[0] + brg1[0]);
      float fB = sigm(acc1[1] + brg1[1]);
      float gB = tanh_(acc1[2] + brg1[2]);
      float oB = sigm(acc1[3] + brg1[3]);
      c_reg[1] = fB * c_reg[1] + iB * gB;
      float hB = oB * tanh_(c_reg[1]);
      pool_acc[1] += hB;
      if (t < S_ - 1) {
        unsigned packed = (unsigned)f2bf(hA) | ((unsigned)f2bf(hB) << 16);
        st_coh_u32((unsigned*)(hout + (size_t)b_own * H2_ + j0), packed);
      }
    }

    if (t < S_ - 1) {
      // convert x_{t+1} to bf16 regs NOW (waits only the vx loads; the h
      // store stays outstanding) so the release drain below waits h only.
      s16x8 pk;
      pk[0] = (short)f2bf(vx0[0]); pk[1] = (short)f2bf(vx0[1]);
      pk[2] = (short)f2bf(vx0[2]); pk[3] = (short)f2bf(vx0[3]);
      pk[4] = (short)f2bf(vx1[0]); pk[5] = (short)f2bf(vx1[1]);
      pk[6] = (short)f2bf(vx1[2]); pk[7] = (short)f2bf(vx1[3]);

      vm_drain();          // release: h store at coherence point
      __syncthreads();     // #B: all waves drained + done reading Alds
      if (tid == 0) st_coh_u32(fgrp + ng, (unsigned)(t + 1));

      // x_{t+1} into LDS (pure LDS op, off the critical drain path)
      *(s16x8*)((char*)Alds + swz_x) = pk;

      // wait: every wave polls the 16 group flags
      const unsigned tgt = (unsigned)(t + 1);
      const unsigned* fp = fgrp + (lane & 15);
      while (!__all(ld_coh_u32(fp) >= tgt))
        __builtin_amdgcn_s_sleep(1);
      // next stage-h LDS writes are ordered vs GEMM by sync #A.
    }
  }

  *(f32x2*)(pooled + (size_t)b_own * H2_ + j0) = pool_acc;
}

// ---------------- fused fc1(relu)+fc2 per batch row -------------------------
__global__ void fc_kernel(const float* __restrict__ pooled,
                          const float* __restrict__ fc1_w, const float* __restrict__ fc1_b,
                          const float* __restrict__ fc2_w, const float* __restrict__ fc2_b,
                          float* __restrict__ out) {
  const int b = blockIdx.x;
  const int tid = threadIdx.x;   // 256
  __shared__ float prow[H2_];
  __shared__ float dec[H2_];
  __shared__ float red[256];
  prow[tid]       = pooled[(size_t)b * H2_ + tid];
  prow[tid + 256] = pooled[(size_t)b * H2_ + tid + 256];
  __syncthreads();
  #pragma unroll
  for (int e = 0; e < 2; ++e) {
    const int o = tid + e * 256;
    const float* wrow = fc1_w + (size_t)o * H2_;
    float a = fc1_b[o];
    #pragma unroll 8
    for (int k = 0; k < H2_; ++k) a += prow[k] * wrow[k];
    dec[o] = fmaxf(a, 0.f);
  }
  __syncthreads();
  red[tid] = dec[tid] * fc2_w[tid] + dec[tid + 256] * fc2_w[tid + 256];
  __syncthreads();
  for (int s = 128; s > 0; s >>= 1) {
    if (tid < s) red[tid] += red[tid + s];
    __syncthreads();
  }
  if (tid == 0) out[b] = red[0] + fc2_b[0];
}

// ---------------- launch -----------------------------------------------------
extern "C" void kernel_launch(void* const* d_in, const int* in_sizes, int n_in,
                              void* d_out, int out_size, void* d_ws, size_t ws_size,
                              hipStream_t stream) {
  const float* x      = (const float*)d_in[0];
  const float* conv_w = (const float*)d_in[1];
  const float* conv_b = (const float*)d_in[2];
  const float* w_ih   = (const float*)d_in[3];
  const float* b_ih   = (const float*)d_in[4];
  const float* w_hh   = (const float*)d_in[5];
  const float* b_hh   = (const float*)d_in[6];
  const float* h0     = (const float*)d_in[7];
  const float* c0     = (const float*)d_in[8];
  const float* fc1_w  = (const float*)d_in[9];
  const float* fc1_b  = (const float*)d_in[10];
  const float* fc2_w  = (const float*)d_in[11];
  const float* fc2_b  = (const float*)d_in[12];
  float* out = (float*)d_out;

  char* ws = (char*)d_ws;
  // ws layout (bytes):
  //   Wc     [2048][640] bf16 : 0        .. 2621440
  //   bias   [2048]      f32  : 2621440  .. 2629632
  //   h_bf [2][256][512] bf16 : 2629632  .. 3153920
  //   pooled [256][512]  f32  : 3153920  .. 3678208
  //   flags  [16][16]    u32  : 3678208  .. 3679232
  unsigned short* Wc    = (unsigned short*)(ws);
  float* bias           = (float*)(ws + 2621440);
  unsigned short* h_bf  = (unsigned short*)(ws + 2629632);
  float* pooled         = (float*)(ws + 3153920);
  unsigned* flags       = (unsigned*)(ws + 3678208);

  prep_kernel<<<dim3(G4_), dim3(128), 0, stream>>>(conv_w, conv_b, w_ih, b_ih,
                                                   w_hh, b_hh, Wc, bias, flags);

  void* args[8];
  args[0] = (void*)&x;    args[1] = (void*)&h0;   args[2] = (void*)&c0;
  args[3] = (void*)&Wc;   args[4] = (void*)&bias; args[5] = (void*)&h_bf;
  args[6] = (void*)&pooled; args[7] = (void*)&flags;
  hipLaunchCooperativeKernel((void*)lstm_kernel, dim3(256), dim3(256), args, 0, stream);

  fc_kernel<<<dim3(B_), dim3(256), 0, stream>>>(pooled, fc1_w, fc1_b, fc2_w, fc2_b, out);
}